// Round 2
// baseline (31445.700 us; speedup 1.0000x reference)
//
#include <hip/hip_runtime.h>
#include <hip/hip_bf16.h>
#include <math.h>

// Problem constants (B,S,E,H,T) = (32, 512, 300, 512, 9)
#define S_LEN 512
#define BATCH 32
#define EDIM  300
#define HDIM  512
#define NTAG  9
#define M_ROWS (S_LEN * BATCH)      // 16384 rows, m = s*32 + b
#define GATES  4096                 // 2 dirs * 4 gates * 512

typedef __hip_bfloat16 bf16;

__device__ __forceinline__ float sigmoidf(float x) { return 1.f / (1.f + expf(-x)); }

// ---- C(MxN) = A(MxK) * Bw(NxK)^T + bias1[n] + bias2[n], C stored bf16 ----
// AMODE 1: A = word_embedding fp32 (B,S,E), row m -> x[(m&31)][(m>>5)][:]
// AMODE 2: A = bf16 rows (M,K) direct
template <int AMODE>
__global__ __launch_bounds__(256) void gemm_nt(const void* __restrict__ Ap,
                                               const float* __restrict__ Bw,
                                               const float* __restrict__ bias1,
                                               const float* __restrict__ bias2,
                                               bf16* __restrict__ C,
                                               int M, int N, int K) {
    __shared__ float As[16][68];   // [k][m], padded (stride 68 keeps float4 16B-aligned)
    __shared__ float Bs[16][68];   // [k][n]
    const int bm = blockIdx.y * 64;
    const int bn = blockIdx.x * 64;
    const int tx = threadIdx.x & 15;
    const int ty = threadIdx.x >> 4;
    float acc[4][4] = {};
    for (int k0 = 0; k0 < K; k0 += 16) {
#pragma unroll
        for (int i = 0; i < 4; i++) {
            int l = threadIdx.x + i * 256;
            int r = l >> 4;          // 0..63
            int kk = l & 15;
            float va = 0.f, vb = 0.f;
            if (k0 + kk < K) {
                int rg = bm + r;
                if (AMODE == 1) {
                    const float* A = (const float*)Ap;
                    va = A[((size_t)(rg & 31) * S_LEN + (rg >> 5)) * EDIM + k0 + kk];
                } else {
                    const bf16* A = (const bf16*)Ap;
                    va = __bfloat162float(A[(size_t)rg * K + k0 + kk]);
                }
                vb = Bw[(size_t)(bn + r) * K + k0 + kk];
            }
            As[kk][r] = va;
            Bs[kk][r] = vb;
        }
        __syncthreads();
#pragma unroll
        for (int kk = 0; kk < 16; kk++) {
            float4 av = *(const float4*)(&As[kk][ty * 4]);
            float4 bv = *(const float4*)(&Bs[kk][tx * 4]);
            float a4[4] = {av.x, av.y, av.z, av.w};
            float b4[4] = {bv.x, bv.y, bv.z, bv.w};
#pragma unroll
            for (int i = 0; i < 4; i++)
#pragma unroll
                for (int jx = 0; jx < 4; jx++) acc[i][jx] += a4[i] * b4[jx];
        }
        __syncthreads();
    }
#pragma unroll
    for (int i = 0; i < 4; i++) {
        int m = bm + ty * 4 + i;
#pragma unroll
        for (int jx = 0; jx < 4; jx++) {
            int n = bn + tx * 4 + jx;
            C[(size_t)m * N + n] = __float2bfloat16(acc[i][jx] + bias1[n] + bias2[n]);
        }
    }
}

// ---- one LSTM time step, both directions. thread = (dir, b, j); 4 gate dots K=512 ----
// xg:    (M_ROWS, 4096) bf16, precomputed x@W_ih^T + b_ih + b_hh, n = dir*2048 + gate*512 + j
// hprev: fp32, 2 ping-pong bufs, each [dir][b][k]
// cst:   fp32 [dir][b][j]
// hseq:  (S_LEN, BATCH, 1024) bf16 layer output, fwd in [0:512), bwd in [512:1024)
__global__ __launch_bounds__(128) void lstm_step(const bf16* __restrict__ xg,
                                                 const float* __restrict__ w_hh,
                                                 float* __restrict__ hprev,
                                                 float* __restrict__ cst,
                                                 bf16* __restrict__ hseq,
                                                 int t) {
    int b   = threadIdx.x & 31;
    int jj  = threadIdx.x >> 5;            // 0..3
    int dir = blockIdx.x >> 7;             // 0..1
    int j   = (blockIdx.x & 127) * 4 + jj; // 0..511
    int s   = dir ? (S_LEN - 1 - t) : t;

    const float* hp = hprev + ((size_t)(t & 1) * 2 * BATCH + (size_t)dir * BATCH + b) * HDIM;
    float*       hw = hprev + ((size_t)((t + 1) & 1) * 2 * BATCH + (size_t)dir * BATCH + b) * HDIM;
    const float* wbase = w_hh + (size_t)dir * 4 * HDIM * HDIM;
    const float* wi = wbase + (size_t)(0 * HDIM + j) * HDIM;
    const float* wf = wbase + (size_t)(1 * HDIM + j) * HDIM;
    const float* wg = wbase + (size_t)(2 * HDIM + j) * HDIM;
    const float* wo = wbase + (size_t)(3 * HDIM + j) * HDIM;

    size_t xoff = ((size_t)s * BATCH + b) * GATES + (size_t)dir * 2048 + j;
    float ai = __bfloat162float(xg[xoff]);
    float af = __bfloat162float(xg[xoff + 512]);
    float ag = __bfloat162float(xg[xoff + 1024]);
    float ao = __bfloat162float(xg[xoff + 1536]);

#pragma unroll 4
    for (int k = 0; k < HDIM; k += 4) {
        float4 h4 = *(const float4*)(hp + k);
        float4 w;
        w = *(const float4*)(wi + k); ai += h4.x * w.x + h4.y * w.y + h4.z * w.z + h4.w * w.w;
        w = *(const float4*)(wf + k); af += h4.x * w.x + h4.y * w.y + h4.z * w.z + h4.w * w.w;
        w = *(const float4*)(wg + k); ag += h4.x * w.x + h4.y * w.y + h4.z * w.z + h4.w * w.w;
        w = *(const float4*)(wo + k); ao += h4.x * w.x + h4.y * w.y + h4.z * w.z + h4.w * w.w;
    }

    size_t ci = ((size_t)dir * BATCH + b) * HDIM + j;
    float c = sigmoidf(af) * cst[ci] + sigmoidf(ai) * tanhf(ag);
    float h = sigmoidf(ao) * tanhf(c);
    cst[ci] = c;
    hw[j] = h;
    hseq[((size_t)s * BATCH + b) * 1024 + (size_t)dir * HDIM + j] = __float2bfloat16(h);
}

// ---- emissions (B,S,T) = h1 (M_ROWS,1024) bf16 @ proj_w(9,1024)^T + proj_b ----
__global__ __launch_bounds__(256) void proj_kernel(const bf16* __restrict__ h1,
                                                   const float* __restrict__ pw,
                                                   const float* __restrict__ pb,
                                                   float* __restrict__ em) {
    __shared__ float wl[NTAG * 1024];
    __shared__ float bl[NTAG];
    for (int i = threadIdx.x; i < NTAG * 1024; i += 256) wl[i] = pw[i];
    if (threadIdx.x < NTAG) bl[threadIdx.x] = pb[threadIdx.x];
    __syncthreads();
    int m = blockIdx.x * 256 + threadIdx.x;  // 0..16383
    int s = m >> 5, b = m & 31;
    const bf16* hr = h1 + (size_t)m * 1024;
    float acc[NTAG] = {};
    for (int k = 0; k < 1024; k += 8) {
        // load 8 bf16 (16B) at once
        uint4 raw = *(const uint4*)(hr + k);
        const bf16* hv = (const bf16*)&raw;
        float hf[8];
#pragma unroll
        for (int u = 0; u < 8; u++) hf[u] = __bfloat162float(hv[u]);
#pragma unroll
        for (int tt = 0; tt < NTAG; tt++) {
            const float* wrow = &wl[tt * 1024 + k];
#pragma unroll
            for (int u = 0; u < 8; u++) acc[tt] += hf[u] * wrow[u];
        }
    }
#pragma unroll
    for (int tt = 0; tt < NTAG; tt++)
        em[((size_t)b * S_LEN + s) * NTAG + tt] = acc[tt] + bl[tt];
}

// ---- CRF NLL per batch element: one block (1 wave) per b; lanes 0..8 hold alpha ----
__global__ __launch_bounds__(64) void crf_kernel(const float* __restrict__ em,
                                                 const int* __restrict__ tags,
                                                 const int* __restrict__ mask,
                                                 const float* __restrict__ trans,
                                                 const float* __restrict__ startv,
                                                 const float* __restrict__ endv,
                                                 float* __restrict__ out_b) {
    int b = blockIdx.x;
    int lane = threadIdx.x;
    const float* E = em + (size_t)b * S_LEN * NTAG;
    const int* tg = tags + (size_t)b * S_LEN;
    const int* mk = mask + (size_t)b * S_LEN;

    // numerator partials + mask count, wave-parallel over s
    float np = 0.f;
    int msum = 0;
    for (int s = lane; s < S_LEN; s += 64) {
        msum += (mk[s] != 0);
        if (s >= 1) {
            float mf = (float)mk[s];
            int ts = tg[s], tp = tg[s - 1];
            np += (E[(size_t)s * NTAG + ts] + trans[tp * NTAG + ts]) * mf;
        }
    }
    for (int off = 32; off; off >>= 1) {
        np += __shfl_down(np, off);
        msum += __shfl_down(msum, off);
    }
    np = __shfl(np, 0);
    msum = __shfl(msum, 0);

    // forward algorithm: lane j (<9) holds alpha[j]
    int j = lane;
    float tcol[NTAG];
    if (j < NTAG)
#pragma unroll
        for (int i = 0; i < NTAG; i++) tcol[i] = trans[i * NTAG + j];
    float alpha = (j < NTAG) ? (startv[j] + E[j]) : -1e30f;
    for (int s = 1; s < S_LEN; s++) {
        float av[NTAG];
#pragma unroll
        for (int i = 0; i < NTAG; i++) av[i] = __shfl(alpha, i);  // all lanes participate
        if (j < NTAG) {
            float m = -1e30f;
#pragma unroll
            for (int i = 0; i < NTAG; i++) m = fmaxf(m, av[i] + tcol[i]);
            float ss = 0.f;
#pragma unroll
            for (int i = 0; i < NTAG; i++) ss += expf(av[i] + tcol[i] - m);
            float nxt = m + logf(ss) + E[(size_t)s * NTAG + j];
            if (mk[s] != 0) alpha = nxt;
        }
    }
    float val = (j < NTAG) ? (alpha + endv[j]) : -1e30f;
    float m2 = -1e30f, vv;
#pragma unroll
    for (int i = 0; i < NTAG; i++) { vv = __shfl(val, i); m2 = fmaxf(m2, vv); }
    float s2 = 0.f;
#pragma unroll
    for (int i = 0; i < NTAG; i++) { vv = __shfl(val, i); s2 += expf(vv - m2); }
    float denom = m2 + logf(s2);
    if (lane == 0) {
        int t0 = tg[0];
        int last = msum - 1;
        if (last < 0) last = 0;
        int lt = tg[last];
        float num = startv[t0] + E[t0] + np + endv[lt];
        out_b[b] = num - denom;
    }
}

__global__ __launch_bounds__(64) void finalize(const float* __restrict__ out_b,
                                               float* __restrict__ out) {
    int lane = threadIdx.x;
    float v = (lane < BATCH) ? out_b[lane] : 0.f;
    for (int off = 32; off; off >>= 1) v += __shfl_down(v, off);
    if (lane == 0) out[0] = -v / (float)BATCH;
}

extern "C" void kernel_launch(void* const* d_in, const int* in_sizes, int n_in,
                              void* d_out, int out_size, void* d_ws, size_t ws_size,
                              hipStream_t stream) {
    const float* x      = (const float*)d_in[0];
    const int*   tags   = (const int*)d_in[1];
    const int*   mask   = (const int*)d_in[2];
    const float* w_ih0  = (const float*)d_in[3];   // (2,2048,300)
    const float* w_hh0  = (const float*)d_in[4];   // (2,2048,512)
    const float* b_ih0  = (const float*)d_in[5];   // (2,2048) -> flat 4096
    const float* b_hh0  = (const float*)d_in[6];
    const float* w_ih1  = (const float*)d_in[7];   // (2,2048,1024)
    const float* w_hh1  = (const float*)d_in[8];
    const float* b_ih1  = (const float*)d_in[9];
    const float* b_hh1  = (const float*)d_in[10];
    const float* pw     = (const float*)d_in[11];  // (9,1024)
    const float* pb     = (const float*)d_in[12];
    const float* trans  = (const float*)d_in[13];  // (9,9)
    const float* startv = (const float*)d_in[14];
    const float* endv   = (const float*)d_in[15];

    // ---- ws layout (bytes). Total ~169 MB. ----
    char* ws = (char*)d_ws;
    size_t off = 0;
    bf16* xg    = (bf16*)(ws + off); off += (size_t)M_ROWS * GATES * 2;   // 134,217,728 B
    bf16* hseq  = (bf16*)(ws + off); off += (size_t)M_ROWS * 1024 * 2;    // 33,554,432 B (h0 then h1, reused)
    float* hprev = (float*)(ws + off); off += (size_t)2 * 2 * BATCH * HDIM * 4; // 262,144 B
    float* cst   = (float*)(ws + off); off += (size_t)2 * BATCH * HDIM * 4;     // 131,072 B (contig after hprev)
    float* emis  = (float*)(ws + off); off += (size_t)BATCH * S_LEN * NTAG * 4; // 589,824 B
    float* outb  = (float*)(ws + off); off += 64 * 4;
    if (off > ws_size) return;  // clean failure signal instead of device fault

    const size_t state_bytes = (size_t)(2 * 2 * BATCH * HDIM + 2 * BATCH * HDIM) * sizeof(float);

    // ---- layer 0 ----
    gemm_nt<1><<<dim3(GATES / 64, M_ROWS / 64), 256, 0, stream>>>(x, w_ih0, b_ih0, b_hh0, xg,
                                                                  M_ROWS, GATES, EDIM);
    hipMemsetAsync(hprev, 0, state_bytes, stream);
    for (int t = 0; t < S_LEN; t++)
        lstm_step<<<256, 128, 0, stream>>>(xg, w_hh0, hprev, cst, hseq, t);

    // ---- layer 1 (h1 overwrites hseq after the input GEMM consumed h0) ----
    gemm_nt<2><<<dim3(GATES / 64, M_ROWS / 64), 256, 0, stream>>>(hseq, w_ih1, b_ih1, b_hh1, xg,
                                                                  M_ROWS, GATES, 1024);
    hipMemsetAsync(hprev, 0, state_bytes, stream);
    for (int t = 0; t < S_LEN; t++)
        lstm_step<<<256, 128, 0, stream>>>(xg, w_hh1, hprev, cst, hseq, t);

    // ---- projection + CRF ----
    proj_kernel<<<M_ROWS / 256, 256, 0, stream>>>(hseq, pw, pb, emis);
    crf_kernel<<<BATCH, 64, 0, stream>>>(emis, tags, mask, trans, startv, endv, outb);
    finalize<<<1, 64, 0, stream>>>(outb, (float*)d_out);
}

// Round 3
// 10436.821 us; speedup vs baseline: 3.0130x; 3.0130x over previous
//
#include <hip/hip_runtime.h>
#include <hip/hip_bf16.h>
#include <math.h>

// Problem constants (B,S,E,H,T) = (32, 512, 300, 512, 9)
#define S_LEN 512
#define BATCH 32
#define HDIM  512
#define NTAG  9
#define M_ROWS (S_LEN * BATCH)      // 16384 rows, m = s*32 + b
#define GATES  4096                 // 2 dirs * 4 gates * 512

typedef __hip_bfloat16 bf16;
typedef float f32x4 __attribute__((ext_vector_type(4)));
typedef float f32x16 __attribute__((ext_vector_type(16)));
typedef short bfrag8 __attribute__((ext_vector_type(8)));   // 8 bf16 = 4 VGPR

typedef __attribute__((address_space(3))) void lvoid;
typedef __attribute__((address_space(1))) void gvoid;
#define GLOAD16(g, l) __builtin_amdgcn_global_load_lds((const gvoid*)(g), (lvoid*)(l), 16, 0, 0)

__device__ __forceinline__ float sigmoidf_(float x) { return 1.f / (1.f + __expf(-x)); }
__device__ __forceinline__ float bf2f(short s) {
    unsigned u = ((unsigned)(unsigned short)s) << 16;
    return __builtin_bit_cast(float, u);
}
__device__ __forceinline__ short f2bf(float f) {
    __hip_bfloat16 h = __float2bfloat16(f);
    return __builtin_bit_cast(short, h);
}

// ============================================================================
// MFMA GEMM: xg(M x 4096) = A(M x K) * Bw(4096 x K)^T + bias1[n] + bias2[n]
// 128x128 tile, BK=64, 4 waves (256 thr), wave = 64x64 quadrant of 16x16x32 MFMAs.
// AMODE 0: A = word_embedding fp32 (B,S,E), row m -> x[(m&31)][(m>>5)][:], K=300 (tiles padded w/ 0)
// AMODE 1: A = bf16 rows (M,1024)
// LDS tiles XOR-swizzled: byte ^ ((row&7)<<4); staged via registers (swizzle on write+read).
// Fragment maps (m89-verified): A row=l&15,k=(l>>4)*8+i ; B col=l&15,k=(l>>4)*8+i ;
//                               C col=l&15, row=(l>>4)*4+reg.
// ============================================================================
template <int AMODE>
__global__ __launch_bounds__(256) void gemm_xg(const void* __restrict__ Ap,
                                               const float* __restrict__ Bw,
                                               int K, int KT,
                                               const float* __restrict__ bias1,
                                               const float* __restrict__ bias2,
                                               short* __restrict__ xg) {
    __shared__ char smem[32768];
    char* As = smem;
    char* Bs = smem + 16384;
    const int tid = threadIdx.x;
    const int bm = blockIdx.y * 128;
    const int bn = blockIdx.x * 128;
    const int l  = tid & 63;
    const int wv = tid >> 6;
    const int wr = wv >> 1, wc = wv & 1;

    f32x4 acc[4][4] = {};

    const int r_st  = tid >> 1;     // staging row 0..127
    const int kh    = tid & 1;      // k-half 0/1 (32 cols each)
    const int xorr  = (r_st & 7) << 4;

    for (int kt = 0; kt < KT; kt++) {
        const int k0 = kt * 64;
        // ---- stage A ----
        if (AMODE == 0) {
            const float* A = (const float*)Ap;
            int mg = bm + r_st;
            const float* arow = A + ((size_t)(mg & 31) * S_LEN + (mg >> 5)) * 300;
#pragma unroll
            for (int u = 0; u < 8; u++) {
                int kk = k0 + kh * 32 + u * 4;
                float4 v = make_float4(0.f, 0.f, 0.f, 0.f);
                if (kk + 4 <= K) v = *(const float4*)(arow + kk);
                short4 sv = make_short4(f2bf(v.x), f2bf(v.y), f2bf(v.z), f2bf(v.w));
                *(short4*)(As + ((r_st * 128 + (kh * 64 + u * 8)) ^ xorr)) = sv;
            }
        } else {
            const short* A = (const short*)Ap;
            const short* arow = A + (size_t)(bm + r_st) * 1024;
#pragma unroll
            for (int u = 0; u < 4; u++) {
                int kk = k0 + kh * 32 + u * 8;
                bfrag8 v = *(const bfrag8*)(arow + kk);
                *(bfrag8*)(As + ((r_st * 128 + (kh * 64 + u * 16)) ^ xorr)) = v;
            }
        }
        // ---- stage B (always fp32 rows, stride K) ----
        {
            const float* brow = Bw + (size_t)(bn + r_st) * K;
#pragma unroll
            for (int u = 0; u < 8; u++) {
                int kk = k0 + kh * 32 + u * 4;
                float4 v = make_float4(0.f, 0.f, 0.f, 0.f);
                if (kk + 4 <= K) v = *(const float4*)(brow + kk);
                short4 sv = make_short4(f2bf(v.x), f2bf(v.y), f2bf(v.z), f2bf(v.w));
                *(short4*)(Bs + ((r_st * 128 + (kh * 64 + u * 8)) ^ xorr)) = sv;
            }
        }
        __syncthreads();
        // ---- compute ----
#pragma unroll
        for (int kf = 0; kf < 2; kf++) {
            bfrag8 af[4], bfr[4];
#pragma unroll
            for (int ms = 0; ms < 4; ms++) {
                int row = wr * 64 + ms * 16 + (l & 15);
                af[ms] = *(const bfrag8*)(As + ((row * 128 + kf * 64 + (l >> 4) * 16) ^ ((row & 7) << 4)));
            }
#pragma unroll
            for (int ns = 0; ns < 4; ns++) {
                int row = wc * 64 + ns * 16 + (l & 15);
                bfr[ns] = *(const bfrag8*)(Bs + ((row * 128 + kf * 64 + (l >> 4) * 16) ^ ((row & 7) << 4)));
            }
#pragma unroll
            for (int ms = 0; ms < 4; ms++)
#pragma unroll
                for (int ns = 0; ns < 4; ns++)
                    acc[ms][ns] = __builtin_amdgcn_mfma_f32_16x16x32_bf16(af[ms], bfr[ns], acc[ms][ns], 0, 0, 0);
        }
        __syncthreads();
    }
    // ---- epilogue ----
#pragma unroll
    for (int ns = 0; ns < 4; ns++) {
        int n = bn + wc * 64 + ns * 16 + (l & 15);
        float bsum = bias1[n] + bias2[n];
#pragma unroll
        for (int ms = 0; ms < 4; ms++) {
#pragma unroll
            for (int r = 0; r < 4; r++) {
                int m = bm + wr * 64 + ms * 16 + (l >> 4) * 4 + r;
                xg[(size_t)m * GATES + n] = f2bf(acc[ms][ns][r] + bsum);
            }
        }
    }
}

// ============================================================================
// Persistent bidirectional LSTM scan for one layer.
// 128 one-wave workgroups: wg = dir*64 + w; wg owns j in [w*8, w*8+8), all 4 gates,
// both handled for all 32 batch rows. Weights (32 x bfrag8 = 128 VGPR) persist in registers.
// h exchanged via pre-swizzled ping-pong publish buffer + per-wg flags (release/acquire).
// MFMA 32x32x16 maps (m74/m101): A row=l&31,k=(l>>5)*8+i ; B col=l&31,k=(l>>5)*8+i ;
//                                C col=l&31, row=(reg&3)+8*(reg>>2)+4*(l>>5).
// ============================================================================
__global__ __launch_bounds__(64, 1) void lstm_scan(const short* __restrict__ xg,
                                                   const float* __restrict__ whh,
                                                   short* __restrict__ pub,     // 2 bufs * 2 dirs * 32*512 bf16
                                                   short* __restrict__ hseq,    // (s*32+b) x 1024
                                                   int* __restrict__ flags) {   // 128
    const int wg   = blockIdx.x;
    const int dir  = wg >> 6;
    const int w    = wg & 63;
    const int lane = threadIdx.x;
    const int jbase = w * 8;
    const int b  = lane & 31;       // batch row (A) / weight col (B)
    const int qh = lane >> 5;       // 0/1

    __shared__ char hst[32768];     // staged h [32 b][512 k] bf16 (swizzled bytes)
    __shared__ float Cb[32][33];    // gate exchange, padded

    // ---- load recurrent weights into registers (once) ----
    const int g  = (lane & 31) >> 3;
    const int jj = lane & 7;
    bfrag8 wf[32];
    {
        const float* sp = whh + ((size_t)dir * 2048 + g * 512 + jbase + jj) * 512;
#pragma unroll
        for (int ks = 0; ks < 32; ks++) {
            const float* p = sp + ks * 16 + qh * 8;
            bfrag8 v;
#pragma unroll
            for (int u = 0; u < 8; u++) v[u] = f2bf(p[u]);
            wf[ks] = v;
        }
    }

    float c4[4] = {0.f, 0.f, 0.f, 0.f};

    for (int t = 0; t < S_LEN; t++) {
        const int s = dir ? (S_LEN - 1 - t) : t;
        // ---- prefetch xg gate pre-activations for this step ----
        float xf[4][4];
#pragma unroll
        for (int q = 0; q < 4; q++) {
            int j = jbase + qh * 4 + q;
#pragma unroll
            for (int gg = 0; gg < 4; gg++)
                xf[q][gg] = bf2f(xg[((size_t)s * BATCH + b) * GATES + dir * 2048 + gg * 512 + j]);
        }
        // ---- wait for h[t] from all 64 wgs of this dir ----
        if (t > 0) {
            int guard = 0;
            for (;;) {
                int v = __hip_atomic_load(&flags[dir * 64 + lane], __ATOMIC_RELAXED,
                                          __HIP_MEMORY_SCOPE_AGENT);
                if (__ballot(v >= t) == 0xFFFFFFFFFFFFFFFFull) break;
                if (++guard > 65536) break;
                __builtin_amdgcn_s_sleep(2);
            }
            __threadfence();   // acquire: make published h visible
        }
        // ---- stage h[t] -> LDS (byte-identical copy; data pre-swizzled) ----
        {
            const char* src = (const char*)pub + ((size_t)((t & 1) * 2 + dir)) * 32768 + lane * 16;
#pragma unroll
            for (int i = 0; i < 32; i++)
                GLOAD16(src + i * 1024, hst + i * 1024);
        }
        asm volatile("s_waitcnt vmcnt(0)" ::: "memory");
        __builtin_amdgcn_sched_barrier(0);
        // ---- MFMA: C(32b x 32rows) = h(32x512) * W^T ----
        f32x16 acc = {};
#pragma unroll
        for (int ks = 0; ks < 32; ks++) {
            const bfrag8 a = *(const bfrag8*)(hst + ((b * 1024 + ks * 32 + qh * 16) ^ ((b & 7) << 4)));
            acc = __builtin_amdgcn_mfma_f32_32x32x16_bf16(a, wf[ks], acc, 0, 0, 0);
        }
        // ---- exchange C through LDS ----
#pragma unroll
        for (int r = 0; r < 16; r++) {
            int brow = (r & 3) + 8 * (r >> 2) + 4 * qh;
            Cb[brow][lane & 31] = acc[r];
        }
        __syncthreads();
        // ---- gates / state update: lane handles (b, jj = qh*4+q) ----
        float hv[4];
#pragma unroll
        for (int q = 0; q < 4; q++) {
            int cj = qh * 4 + q;
            float gi = Cb[b][0 * 8 + cj] + xf[q][0];
            float gf = Cb[b][1 * 8 + cj] + xf[q][1];
            float gc = Cb[b][2 * 8 + cj] + xf[q][2];
            float go = Cb[b][3 * 8 + cj] + xf[q][3];
            float cc = sigmoidf_(gf) * c4[q] + sigmoidf_(gi) * tanhf(gc);
            c4[q] = cc;
            hv[q] = sigmoidf_(go) * tanhf(cc);
        }
        short4 hq = make_short4(f2bf(hv[0]), f2bf(hv[1]), f2bf(hv[2]), f2bf(hv[3]));
        // ---- publish h[t+1] (pre-swizzled) + hseq ----
        int j0 = jbase + qh * 4;
        {
            char* pdst = (char*)pub + ((size_t)(((t + 1) & 1) * 2 + dir)) * 32768 +
                         ((b * 1024 + j0 * 2) ^ ((b & 7) << 4));
            *(short4*)pdst = hq;
            *(short4*)(hseq + ((size_t)s * BATCH + b) * 1024 + dir * HDIM + j0) = hq;
        }
        asm volatile("s_waitcnt vmcnt(0)" ::: "memory");
        __threadfence();   // release: publish before flag
        if (lane == 0)
            __hip_atomic_store(&flags[dir * 64 + w], t + 1, __ATOMIC_RELAXED,
                               __HIP_MEMORY_SCOPE_AGENT);
        __syncthreads();
    }
}

// ---- emissions (B,S,T) = h1 (M_ROWS,1024) bf16 @ proj_w(9,1024)^T + proj_b ----
__global__ __launch_bounds__(256) void proj_kernel(const bf16* __restrict__ h1,
                                                   const float* __restrict__ pw,
                                                   const float* __restrict__ pb,
                                                   float* __restrict__ em) {
    __shared__ float wl[NTAG * 1024];
    __shared__ float bl[NTAG];
    for (int i = threadIdx.x; i < NTAG * 1024; i += 256) wl[i] = pw[i];
    if (threadIdx.x < NTAG) bl[threadIdx.x] = pb[threadIdx.x];
    __syncthreads();
    int m = blockIdx.x * 256 + threadIdx.x;
    int s = m >> 5, b = m & 31;
    const bf16* hr = h1 + (size_t)m * 1024;
    float acc[NTAG] = {};
    for (int k = 0; k < 1024; k += 8) {
        uint4 raw = *(const uint4*)(hr + k);
        const bf16* hv = (const bf16*)&raw;
        float hf[8];
#pragma unroll
        for (int u = 0; u < 8; u++) hf[u] = __bfloat162float(hv[u]);
#pragma unroll
        for (int tt = 0; tt < NTAG; tt++) {
            const float* wrow = &wl[tt * 1024 + k];
#pragma unroll
            for (int u = 0; u < 8; u++) acc[tt] += hf[u] * wrow[u];
        }
    }
#pragma unroll
    for (int tt = 0; tt < NTAG; tt++)
        em[((size_t)b * S_LEN + s) * NTAG + tt] = acc[tt] + bl[tt];
}

// ---- CRF NLL per batch element ----
__global__ __launch_bounds__(64) void crf_kernel(const float* __restrict__ em,
                                                 const int* __restrict__ tags,
                                                 const int* __restrict__ mask,
                                                 const float* __restrict__ trans,
                                                 const float* __restrict__ startv,
                                                 const float* __restrict__ endv,
                                                 float* __restrict__ out_b) {
    int b = blockIdx.x;
    int lane = threadIdx.x;
    const float* E = em + (size_t)b * S_LEN * NTAG;
    const int* tg = tags + (size_t)b * S_LEN;
    const int* mk = mask + (size_t)b * S_LEN;

    float np = 0.f;
    int msum = 0;
    for (int s = lane; s < S_LEN; s += 64) {
        msum += (mk[s] != 0);
        if (s >= 1) {
            float mf = (float)mk[s];
            int ts = tg[s], tp = tg[s - 1];
            np += (E[(size_t)s * NTAG + ts] + trans[tp * NTAG + ts]) * mf;
        }
    }
    for (int off = 32; off; off >>= 1) {
        np += __shfl_down(np, off);
        msum += __shfl_down(msum, off);
    }
    np = __shfl(np, 0);
    msum = __shfl(msum, 0);

    int j = lane;
    float tcol[NTAG];
    if (j < NTAG)
#pragma unroll
        for (int i = 0; i < NTAG; i++) tcol[i] = trans[i * NTAG + j];
    float alpha = (j < NTAG) ? (startv[j] + E[j]) : -1e30f;
    for (int s = 1; s < S_LEN; s++) {
        float av[NTAG];
#pragma unroll
        for (int i = 0; i < NTAG; i++) av[i] = __shfl(alpha, i);
        if (j < NTAG) {
            float m = -1e30f;
#pragma unroll
            for (int i = 0; i < NTAG; i++) m = fmaxf(m, av[i] + tcol[i]);
            float ss = 0.f;
#pragma unroll
            for (int i = 0; i < NTAG; i++) ss += __expf(av[i] + tcol[i] - m);
            float nxt = m + __logf(ss) + E[(size_t)s * NTAG + j];
            if (mk[s] != 0) alpha = nxt;
        }
    }
    float val = (j < NTAG) ? (alpha + endv[j]) : -1e30f;
    float m2 = -1e30f, vv;
#pragma unroll
    for (int i = 0; i < NTAG; i++) { vv = __shfl(val, i); m2 = fmaxf(m2, vv); }
    float s2 = 0.f;
#pragma unroll
    for (int i = 0; i < NTAG; i++) { vv = __shfl(val, i); s2 += __expf(vv - m2); }
    float denom = m2 + __logf(s2);
    if (lane == 0) {
        int t0 = tg[0];
        int last = msum - 1;
        if (last < 0) last = 0;
        int lt = tg[last];
        float num = startv[t0] + E[t0] + np + endv[lt];
        out_b[b] = num - denom;
    }
}

__global__ __launch_bounds__(64) void finalize(const float* __restrict__ out_b,
                                               float* __restrict__ out) {
    int lane = threadIdx.x;
    float v = (lane < BATCH) ? out_b[lane] : 0.f;
    for (int off = 32; off; off >>= 1) v += __shfl_down(v, off);
    if (lane == 0) out[0] = -v / (float)BATCH;
}

extern "C" void kernel_launch(void* const* d_in, const int* in_sizes, int n_in,
                              void* d_out, int out_size, void* d_ws, size_t ws_size,
                              hipStream_t stream) {
    const float* x      = (const float*)d_in[0];
    const int*   tags   = (const int*)d_in[1];
    const int*   mask   = (const int*)d_in[2];
    const float* w_ih0  = (const float*)d_in[3];   // (2,2048,300)
    const float* w_hh0  = (const float*)d_in[4];   // (2,2048,512)
    const float* b_ih0  = (const float*)d_in[5];
    const float* b_hh0  = (const float*)d_in[6];
    const float* w_ih1  = (const float*)d_in[7];   // (2,2048,1024)
    const float* w_hh1  = (const float*)d_in[8];
    const float* b_ih1  = (const float*)d_in[9];
    const float* b_hh1  = (const float*)d_in[10];
    const float* pw     = (const float*)d_in[11];
    const float* pb     = (const float*)d_in[12];
    const float* trans  = (const float*)d_in[13];
    const float* startv = (const float*)d_in[14];
    const float* endv   = (const float*)d_in[15];

    // ---- ws layout (bytes). Total ~168.5 MB (< known-good 168.76 MB). ----
    char* ws = (char*)d_ws;
    size_t off = 0;
    short* xg    = (short*)(ws + off); off += (size_t)M_ROWS * GATES * 2;   // 134,217,728
    short* hseq  = (short*)(ws + off); off += (size_t)M_ROWS * 1024 * 2;    //  33,554,432
    short* pub   = (short*)(ws + off); off += (size_t)2 * 2 * BATCH * HDIM * 2; // 131,072
    int*   flags = (int*)(ws + off);   off += 4096;                          // 128 used
    float* emis  = (float*)(ws + off); off += (size_t)BATCH * S_LEN * NTAG * 4; // 589,824
    float* outb  = (float*)(ws + off); off += 256;
    if (off > ws_size) return;

    const size_t sync_bytes = (size_t)2 * 2 * BATCH * HDIM * 2 + 4096; // pub + flags (adjacent)

    // ---- layer 0 ----
    gemm_xg<0><<<dim3(32, 128), 256, 0, stream>>>(x, w_ih0, 300, 5, b_ih0, b_hh0, xg);
    hipMemsetAsync(pub, 0, sync_bytes, stream);
    lstm_scan<<<128, 64, 0, stream>>>(xg, w_hh0, pub, hseq, flags);

    // ---- layer 1 ----
    gemm_xg<1><<<dim3(32, 128), 256, 0, stream>>>(hseq, w_ih1, 1024, 16, b_ih1, b_hh1, xg);
    hipMemsetAsync(pub, 0, sync_bytes, stream);
    lstm_scan<<<128, 64, 0, stream>>>(xg, w_hh1, pub, hseq, flags);

    // ---- projection + CRF ----
    proj_kernel<<<M_ROWS / 256, 256, 0, stream>>>((const bf16*)hseq, pw, pb, emis);
    crf_kernel<<<BATCH, 64, 0, stream>>>(emis, tags, mask, trans, startv, endv, outb);
    finalize<<<1, 64, 0, stream>>>(outb, (float*)d_out);
}

// Round 4
// 8457.269 us; speedup vs baseline: 3.7182x; 1.2341x over previous
//
#include <hip/hip_runtime.h>
#include <hip/hip_bf16.h>
#include <math.h>

// Problem constants (B,S,E,H,T) = (32, 512, 300, 512, 9)
#define S_LEN 512
#define BATCH 32
#define HDIM  512
#define NTAG  9
#define M_ROWS (S_LEN * BATCH)      // 16384 rows, m = s*32 + b
#define GATES  4096                 // 2 dirs * 4 gates * 512

typedef __hip_bfloat16 bf16;
typedef unsigned long long ull;
typedef float f32x4 __attribute__((ext_vector_type(4)));
typedef float f32x16 __attribute__((ext_vector_type(16)));
typedef short bfrag8 __attribute__((ext_vector_type(8)));   // 8 bf16 = 4 VGPR

__device__ __forceinline__ float sigmoidf_(float x) { return 1.f / (1.f + __expf(-x)); }
__device__ __forceinline__ float bf2f(short s) {
    unsigned u = ((unsigned)(unsigned short)s) << 16;
    return __builtin_bit_cast(float, u);
}
__device__ __forceinline__ short f2bf(float f) {
    __hip_bfloat16 h = __float2bfloat16(f);
    return __builtin_bit_cast(short, h);
}

// ============================================================================
// MFMA GEMM: xg(M x 4096) = A(M x K) * Bw(4096 x K)^T + bias1[n] + bias2[n]
// (unchanged from round 3 — verified absmax 0)
// ============================================================================
template <int AMODE>
__global__ __launch_bounds__(256) void gemm_xg(const void* __restrict__ Ap,
                                               const float* __restrict__ Bw,
                                               int K, int KT,
                                               const float* __restrict__ bias1,
                                               const float* __restrict__ bias2,
                                               short* __restrict__ xg) {
    __shared__ char smem[32768];
    char* As = smem;
    char* Bs = smem + 16384;
    const int tid = threadIdx.x;
    const int bm = blockIdx.y * 128;
    const int bn = blockIdx.x * 128;
    const int l  = tid & 63;
    const int wv = tid >> 6;
    const int wr = wv >> 1, wc = wv & 1;

    f32x4 acc[4][4] = {};

    const int r_st  = tid >> 1;     // staging row 0..127
    const int kh    = tid & 1;      // k-half 0/1 (32 cols each)
    const int xorr  = (r_st & 7) << 4;

    for (int kt = 0; kt < KT; kt++) {
        const int k0 = kt * 64;
        if (AMODE == 0) {
            const float* A = (const float*)Ap;
            int mg = bm + r_st;
            const float* arow = A + ((size_t)(mg & 31) * S_LEN + (mg >> 5)) * 300;
#pragma unroll
            for (int u = 0; u < 8; u++) {
                int kk = k0 + kh * 32 + u * 4;
                float4 v = make_float4(0.f, 0.f, 0.f, 0.f);
                if (kk + 4 <= K) v = *(const float4*)(arow + kk);
                short4 sv = make_short4(f2bf(v.x), f2bf(v.y), f2bf(v.z), f2bf(v.w));
                *(short4*)(As + ((r_st * 128 + (kh * 64 + u * 8)) ^ xorr)) = sv;
            }
        } else {
            const short* A = (const short*)Ap;
            const short* arow = A + (size_t)(bm + r_st) * 1024;
#pragma unroll
            for (int u = 0; u < 4; u++) {
                int kk = k0 + kh * 32 + u * 8;
                bfrag8 v = *(const bfrag8*)(arow + kk);
                *(bfrag8*)(As + ((r_st * 128 + (kh * 64 + u * 16)) ^ xorr)) = v;
            }
        }
        {
            const float* brow = Bw + (size_t)(bn + r_st) * K;
#pragma unroll
            for (int u = 0; u < 8; u++) {
                int kk = k0 + kh * 32 + u * 4;
                float4 v = make_float4(0.f, 0.f, 0.f, 0.f);
                if (kk + 4 <= K) v = *(const float4*)(brow + kk);
                short4 sv = make_short4(f2bf(v.x), f2bf(v.y), f2bf(v.z), f2bf(v.w));
                *(short4*)(Bs + ((r_st * 128 + (kh * 64 + u * 8)) ^ xorr)) = sv;
            }
        }
        __syncthreads();
#pragma unroll
        for (int kf = 0; kf < 2; kf++) {
            bfrag8 af[4], bfr[4];
#pragma unroll
            for (int ms = 0; ms < 4; ms++) {
                int row = wr * 64 + ms * 16 + (l & 15);
                af[ms] = *(const bfrag8*)(As + ((row * 128 + kf * 64 + (l >> 4) * 16) ^ ((row & 7) << 4)));
            }
#pragma unroll
            for (int ns = 0; ns < 4; ns++) {
                int row = wc * 64 + ns * 16 + (l & 15);
                bfr[ns] = *(const bfrag8*)(Bs + ((row * 128 + kf * 64 + (l >> 4) * 16) ^ ((row & 7) << 4)));
            }
#pragma unroll
            for (int ms = 0; ms < 4; ms++)
#pragma unroll
                for (int ns = 0; ns < 4; ns++)
                    acc[ms][ns] = __builtin_amdgcn_mfma_f32_16x16x32_bf16(af[ms], bfr[ns], acc[ms][ns], 0, 0, 0);
        }
        __syncthreads();
    }
#pragma unroll
    for (int ns = 0; ns < 4; ns++) {
        int n = bn + wc * 64 + ns * 16 + (l & 15);
        float bsum = bias1[n] + bias2[n];
#pragma unroll
        for (int ms = 0; ms < 4; ms++) {
#pragma unroll
            for (int r = 0; r < 4; r++) {
                int m = bm + wr * 64 + ms * 16 + (l >> 4) * 4 + r;
                xg[(size_t)m * GATES + n] = f2bf(acc[ms][ns][r] + bsum);
            }
        }
    }
}

// ============================================================================
// Persistent bidirectional LSTM scan, v2: 16 wgs x 512 thr (8 waves).
// wg = dir*8 + p; wg owns j in [p*64, p*64+64) for all 4 gates.
// Wave wv: gate g = wv>>1, j-subtile jb = (wv&1)*32. Weights: 32 bfrag8/lane (128 VGPR).
// h exchange: pub buffer accessed ONLY via agent-scope 8B atomics (coherence at L3,
// no fences); per-wg flag released after __syncthreads (drains vmcnt).
// LDS h-tile swizzled ^((b&15)<<4) on both ds_write and ds_read sides.
// MFMA 32x32x16 maps as round-3 (verified): A row=l&31,k=(l>>5)*8+i; B col=l&31,same k;
// C col(l&31)=n, row=(r&3)+8*(r>>2)+4*(l>>5)=b.
// ============================================================================
__global__ __launch_bounds__(512, 2) void lstm_scan(const short* __restrict__ xg,
                                                    const float* __restrict__ whh,
                                                    ull* __restrict__ pub,     // 2 slots * 2 dirs * 4096 ull
                                                    short* __restrict__ hseq,  // (s*32+b) x 1024
                                                    int* __restrict__ flags) { // 16
    const int wg  = blockIdx.x;
    const int dir = wg >> 3;
    const int p   = wg & 7;
    const int tid = threadIdx.x;
    const int wv  = tid >> 6;
    const int l   = tid & 63;
    const int g   = wv >> 1;            // gate 0..3
    const int jb  = (wv & 1) * 32;      // j subtile within wg
    const int qh  = l >> 5;             // k-half for fragments
    const int col = l & 31;

    __shared__ char hst[32768];         // h staged [32 b][1024 B], XOR-swizzled
    __shared__ float Cb[4][32][64];     // [gate][b][jloc]

    // ---- load recurrent weights into registers (once) ----
    bfrag8 wf[32];
    {
        const int n_row = g * 512 + p * 64 + jb + col;
        const float* sp = whh + ((size_t)dir * 2048 + n_row) * 512;
#pragma unroll
        for (int ks = 0; ks < 32; ks++) {
            const float* q = sp + ks * 16 + qh * 8;
            bfrag8 v;
#pragma unroll
            for (int u = 0; u < 8; u++) v[u] = f2bf(q[u]);
            wf[ks] = v;
        }
    }

    // ---- gate/state thread map: (b = tid>>4, jq = tid&15) -> 4 j's ----
    const int bg = tid >> 4;
    const int jq = tid & 15;
    float c4[4] = {0.f, 0.f, 0.f, 0.f};

    // xg prefetch double buffer
    short4 xr_cur[4], xr_nxt[4];
    {
        const int s0 = dir ? (S_LEN - 1) : 0;
        size_t xoff = ((size_t)s0 * BATCH + bg) * GATES + dir * 2048 + p * 64 + jq * 4;
#pragma unroll
        for (int g2 = 0; g2 < 4; g2++) xr_cur[g2] = *(const short4*)(xg + xoff + g2 * 512);
    }

    const int fl = l & 7;   // flag index this lane polls

    for (int t = 0; t < S_LEN; t++) {
        const int s = dir ? (S_LEN - 1 - t) : t;
        // ---- prefetch xg for t+1 (latency hides under spin+gather) ----
        {
            const int tn = (t + 1 < S_LEN) ? t + 1 : t;
            const int sn = dir ? (S_LEN - 1 - tn) : tn;
            size_t xoff = ((size_t)sn * BATCH + bg) * GATES + dir * 2048 + p * 64 + jq * 4;
#pragma unroll
            for (int g2 = 0; g2 < 4; g2++) xr_nxt[g2] = *(const short4*)(xg + xoff + g2 * 512);
        }
        // ---- wait for h[t] from the 8 wgs of this dir ----
        if (t > 0) {
            const int* fp = flags + dir * 8 + fl;
            int guard = 0;
            for (;;) {
                int v = __hip_atomic_load(fp, __ATOMIC_RELAXED, __HIP_MEMORY_SCOPE_AGENT);
                if (__all(v >= t)) break;
                if (++guard > (1 << 18)) break;
                __builtin_amdgcn_s_sleep(2);
            }
        }
        // ---- gather h[t] (L3-coherent atomic loads) -> LDS (swizzled) ----
        {
            const ull* src = pub + (size_t)((t & 1) * 2 + dir) * 4096;
#pragma unroll
            for (int i = 0; i < 8; i++) {
                int idx = tid + i * 512;
                ull v = __hip_atomic_load(src + idx, __ATOMIC_RELAXED, __HIP_MEMORY_SCOPE_AGENT);
                int byte = idx * 8;
                int b = byte >> 10;
                *(ull*)(hst + (byte ^ ((b & 15) << 4))) = v;
            }
        }
        __syncthreads();
        // ---- MFMA: C(32b x 32n) += h(32x512) * W^T ----
        f32x16 acc = {};
#pragma unroll
        for (int ks = 0; ks < 32; ks++) {
            int byte = col * 1024 + ks * 32 + qh * 16;
            const bfrag8 a = *(const bfrag8*)(hst + (byte ^ ((col & 15) << 4)));
            acc = __builtin_amdgcn_mfma_f32_32x32x16_bf16(a, wf[ks], acc, 0, 0, 0);
        }
        // ---- exchange C through LDS ----
#pragma unroll
        for (int r = 0; r < 16; r++) {
            int brow = (r & 3) + 8 * (r >> 2) + 4 * qh;
            Cb[g][brow][jb + col] = acc[r];
        }
        __syncthreads();
        // ---- gates / state update ----
        float hv[4];
        {
            float xi[4] = {bf2f(xr_cur[0].x), bf2f(xr_cur[0].y), bf2f(xr_cur[0].z), bf2f(xr_cur[0].w)};
            float xf[4] = {bf2f(xr_cur[1].x), bf2f(xr_cur[1].y), bf2f(xr_cur[1].z), bf2f(xr_cur[1].w)};
            float xc[4] = {bf2f(xr_cur[2].x), bf2f(xr_cur[2].y), bf2f(xr_cur[2].z), bf2f(xr_cur[2].w)};
            float xo[4] = {bf2f(xr_cur[3].x), bf2f(xr_cur[3].y), bf2f(xr_cur[3].z), bf2f(xr_cur[3].w)};
#pragma unroll
            for (int q = 0; q < 4; q++) {
                int jl = jq * 4 + q;
                float gi = Cb[0][bg][jl] + xi[q];
                float gf = Cb[1][bg][jl] + xf[q];
                float gc = Cb[2][bg][jl] + xc[q];
                float go = Cb[3][bg][jl] + xo[q];
                float cc = sigmoidf_(gf) * c4[q] + sigmoidf_(gi) * tanhf(gc);
                c4[q] = cc;
                hv[q] = sigmoidf_(go) * tanhf(cc);
            }
        }
        // ---- publish h[t+1] + hseq ----
        {
            ull pk = (ull)(unsigned short)f2bf(hv[0]) |
                     ((ull)(unsigned short)f2bf(hv[1]) << 16) |
                     ((ull)(unsigned short)f2bf(hv[2]) << 32) |
                     ((ull)(unsigned short)f2bf(hv[3]) << 48);
            ull* dst = pub + (size_t)(((t + 1) & 1) * 2 + dir) * 4096 + bg * 128 + p * 16 + jq;
            __hip_atomic_store(dst, pk, __ATOMIC_RELAXED, __HIP_MEMORY_SCOPE_AGENT);
            ull* hd = (ull*)(hseq + ((size_t)s * BATCH + bg) * 1024 + dir * HDIM + p * 64 + jq * 4);
            __builtin_nontemporal_store(pk, hd);
        }
        // swap prefetch buffers
#pragma unroll
        for (int g2 = 0; g2 < 4; g2++) xr_cur[g2] = xr_nxt[g2];
        // ---- barrier drains all waves' vmcnt, then release the flag ----
        __syncthreads();
        if (tid == 0)
            __hip_atomic_store(flags + dir * 8 + p, t + 1, __ATOMIC_RELEASE,
                               __HIP_MEMORY_SCOPE_AGENT);
    }
}

// ---- emissions (B,S,T) = h1 (M_ROWS,1024) bf16 @ proj_w(9,1024)^T + proj_b ----
__global__ __launch_bounds__(256) void proj_kernel(const bf16* __restrict__ h1,
                                                   const float* __restrict__ pw,
                                                   const float* __restrict__ pb,
                                                   float* __restrict__ em) {
    __shared__ float wl[NTAG * 1024];
    __shared__ float bl[NTAG];
    for (int i = threadIdx.x; i < NTAG * 1024; i += 256) wl[i] = pw[i];
    if (threadIdx.x < NTAG) bl[threadIdx.x] = pb[threadIdx.x];
    __syncthreads();
    int m = blockIdx.x * 256 + threadIdx.x;
    int s = m >> 5, b = m & 31;
    const bf16* hr = h1 + (size_t)m * 1024;
    float acc[NTAG] = {};
    for (int k = 0; k < 1024; k += 8) {
        uint4 raw = *(const uint4*)(hr + k);
        const bf16* hv = (const bf16*)&raw;
        float hf[8];
#pragma unroll
        for (int u = 0; u < 8; u++) hf[u] = __bfloat162float(hv[u]);
#pragma unroll
        for (int tt = 0; tt < NTAG; tt++) {
            const float* wrow = &wl[tt * 1024 + k];
#pragma unroll
            for (int u = 0; u < 8; u++) acc[tt] += hf[u] * wrow[u];
        }
    }
#pragma unroll
    for (int tt = 0; tt < NTAG; tt++)
        em[((size_t)b * S_LEN + s) * NTAG + tt] = acc[tt] + bl[tt];
}

// ---- CRF NLL per batch element ----
__global__ __launch_bounds__(64) void crf_kernel(const float* __restrict__ em,
                                                 const int* __restrict__ tags,
                                                 const int* __restrict__ mask,
                                                 const float* __restrict__ trans,
                                                 const float* __restrict__ startv,
                                                 const float* __restrict__ endv,
                                                 float* __restrict__ out_b) {
    int b = blockIdx.x;
    int lane = threadIdx.x;
    const float* E = em + (size_t)b * S_LEN * NTAG;
    const int* tg = tags + (size_t)b * S_LEN;
    const int* mk = mask + (size_t)b * S_LEN;

    float np = 0.f;
    int msum = 0;
    for (int s = lane; s < S_LEN; s += 64) {
        msum += (mk[s] != 0);
        if (s >= 1) {
            float mf = (float)mk[s];
            int ts = tg[s], tp = tg[s - 1];
            np += (E[(size_t)s * NTAG + ts] + trans[tp * NTAG + ts]) * mf;
        }
    }
    for (int off = 32; off; off >>= 1) {
        np += __shfl_down(np, off);
        msum += __shfl_down(msum, off);
    }
    np = __shfl(np, 0);
    msum = __shfl(msum, 0);

    int j = lane;
    float tcol[NTAG];
    if (j < NTAG)
#pragma unroll
        for (int i = 0; i < NTAG; i++) tcol[i] = trans[i * NTAG + j];
    float alpha = (j < NTAG) ? (startv[j] + E[j]) : -1e30f;
    for (int s = 1; s < S_LEN; s++) {
        float av[NTAG];
#pragma unroll
        for (int i = 0; i < NTAG; i++) av[i] = __shfl(alpha, i);
        if (j < NTAG) {
            float m = -1e30f;
#pragma unroll
            for (int i = 0; i < NTAG; i++) m = fmaxf(m, av[i] + tcol[i]);
            float ss = 0.f;
#pragma unroll
            for (int i = 0; i < NTAG; i++) ss += __expf(av[i] + tcol[i] - m);
            float nxt = m + __logf(ss) + E[(size_t)s * NTAG + j];
            if (mk[s] != 0) alpha = nxt;
        }
    }
    float val = (j < NTAG) ? (alpha + endv[j]) : -1e30f;
    float m2 = -1e30f, vv;
#pragma unroll
    for (int i = 0; i < NTAG; i++) { vv = __shfl(val, i); m2 = fmaxf(m2, vv); }
    float s2 = 0.f;
#pragma unroll
    for (int i = 0; i < NTAG; i++) { vv = __shfl(val, i); s2 += __expf(vv - m2); }
    float denom = m2 + __logf(s2);
    if (lane == 0) {
        int t0 = tg[0];
        int last = msum - 1;
        if (last < 0) last = 0;
        int lt = tg[last];
        float num = startv[t0] + E[t0] + np + endv[lt];
        out_b[b] = num - denom;
    }
}

__global__ __launch_bounds__(64) void finalize(const float* __restrict__ out_b,
                                               float* __restrict__ out) {
    int lane = threadIdx.x;
    float v = (lane < BATCH) ? out_b[lane] : 0.f;
    for (int off = 32; off; off >>= 1) v += __shfl_down(v, off);
    if (lane == 0) out[0] = -v / (float)BATCH;
}

extern "C" void kernel_launch(void* const* d_in, const int* in_sizes, int n_in,
                              void* d_out, int out_size, void* d_ws, size_t ws_size,
                              hipStream_t stream) {
    const float* x      = (const float*)d_in[0];
    const int*   tags   = (const int*)d_in[1];
    const int*   mask   = (const int*)d_in[2];
    const float* w_ih0  = (const float*)d_in[3];   // (2,2048,300)
    const float* w_hh0  = (const float*)d_in[4];   // (2,2048,512)
    const float* b_ih0  = (const float*)d_in[5];
    const float* b_hh0  = (const float*)d_in[6];
    const float* w_ih1  = (const float*)d_in[7];   // (2,2048,1024)
    const float* w_hh1  = (const float*)d_in[8];
    const float* b_ih1  = (const float*)d_in[9];
    const float* b_hh1  = (const float*)d_in[10];
    const float* pw     = (const float*)d_in[11];
    const float* pb     = (const float*)d_in[12];
    const float* trans  = (const float*)d_in[13];
    const float* startv = (const float*)d_in[14];
    const float* endv   = (const float*)d_in[15];

    // ---- ws layout (bytes). Total ~168.5 MB. ----
    char* ws = (char*)d_ws;
    size_t off = 0;
    short* xg    = (short*)(ws + off); off += (size_t)M_ROWS * GATES * 2;   // 134,217,728
    short* hseq  = (short*)(ws + off); off += (size_t)M_ROWS * 1024 * 2;    //  33,554,432
    ull*   pub   = (ull*)(ws + off);   off += (size_t)2 * 2 * 4096 * 8;     //     131,072
    int*   flags = (int*)(ws + off);   off += 4096;                          //      16 used
    float* emis  = (float*)(ws + off); off += (size_t)BATCH * S_LEN * NTAG * 4; // 589,824
    float* outb  = (float*)(ws + off); off += 256;
    if (off > ws_size) return;

    const size_t sync_bytes = (size_t)2 * 2 * 4096 * 8 + 4096; // pub + flags (adjacent)

    // ---- layer 0 ----
    gemm_xg<0><<<dim3(32, 128), 256, 0, stream>>>(x, w_ih0, 300, 5, b_ih0, b_hh0, xg);
    hipMemsetAsync(pub, 0, sync_bytes, stream);
    lstm_scan<<<16, 512, 0, stream>>>(xg, w_hh0, pub, hseq, flags);

    // ---- layer 1 ----
    gemm_xg<1><<<dim3(32, 128), 256, 0, stream>>>(hseq, w_ih1, 1024, 16, b_ih1, b_hh1, xg);
    hipMemsetAsync(pub, 0, sync_bytes, stream);
    lstm_scan<<<16, 512, 0, stream>>>(xg, w_hh1, pub, hseq, flags);

    // ---- projection + CRF ----
    proj_kernel<<<M_ROWS / 256, 256, 0, stream>>>((const bf16*)hseq, pw, pb, emis);
    crf_kernel<<<BATCH, 64, 0, stream>>>(emis, tags, mask, trans, startv, endv, outb);
    finalize<<<1, 64, 0, stream>>>(outb, (float*)d_out);
}